// Round 12
// baseline (1454.572 us; speedup 1.0000x reference)
//
#include <hip/hip_runtime.h>
#include <hip/hip_bf16.h>
#include <math.h>

// Problem constants
#define NSEQ 2048
#define TT   128
#define EE   128
#define HH   256
#define GG   1024
#define LL   1000
#define NT   576        // 8 compute waves + 1 dedicated poller wave
#define NGRP 32         // groups of 64 seqs
#define NMEM 8          // members (blocks) per group; member owns 32 h-units
#define SEQG 64
#define NKT  12         // K-tiles of 32: 4 x + 8 h
#define NMT  64
#define NKT_O 8
#define WSA_ELEMS (NMT * NKT * 64 * 8)      // 768 KB bf16
#define WSO_ELEMS (NMT * NKT_O * 64 * 8)    // 512 KB bf16
// ghf: [grp][member][parity][cg][64 lanes][8 shorts] = 2 MB
#define GHF_SHORTS ((size_t)NGRP * NMEM * 2 * 4 * 64 * 8)
#define NTAGS (NGRP * 64)                   // 64 per-wave tags per group (4 lines)

typedef __attribute__((ext_vector_type(8))) short bf16x8;
typedef __attribute__((ext_vector_type(4))) float f32x4;
typedef unsigned long long u64;

__device__ __forceinline__ unsigned short f2bf(float f) {
    union { float f; unsigned u; } v; v.f = f;
    unsigned r = v.u + 0x7FFF + ((v.u >> 16) & 1);   // RNE
    return (unsigned short)(r >> 16);
}
__device__ __forceinline__ float sigf(float x) { return 1.0f / (1.0f + __expf(-x)); }
__device__ __forceinline__ float tanh_fast(float x) { return 1.0f - 2.0f / (1.0f + __expf(2.0f * x)); }

// system-scope relaxed ops: sc0+sc1 (served at coherence point) — NO wbl2/inv
__device__ __forceinline__ void st8_sys(unsigned short* p, unsigned lo, unsigned hi) {
    u64 v = (u64)lo | ((u64)hi << 32);
    __hip_atomic_store((u64*)p, v, __ATOMIC_RELAXED, __HIP_MEMORY_SCOPE_SYSTEM);
}
__device__ __forceinline__ bf16x8 ld16_sys(const unsigned short* p) {
    u64 lo = __hip_atomic_load((const u64*)p,       __ATOMIC_RELAXED, __HIP_MEMORY_SCOPE_SYSTEM);
    u64 hi = __hip_atomic_load((const u64*)(p + 4), __ATOMIC_RELAXED, __HIP_MEMORY_SCOPE_SYSTEM);
    union { u64 q[2]; bf16x8 v; } u; u.q[0] = lo; u.q[1] = hi;
    return u.v;
}

// init: out zeros, all tags = 1 (h(0) available), ghf parity-0 data = 0.
// Kernel-boundary writeback makes these visible to sc0sc1 loads.
__global__ void init_all_kernel(float* out, int* tags, unsigned short* ghf) {
    int i = blockIdx.x * blockDim.x + threadIdx.x;   // 256*512 = 131072 threads
    if (i < HH + 1) out[i] = 0.0f;
    if (i < NTAGS) tags[i] = 1;
    int gm = i >> 9, j = i & 511;                    // 256 (grp,member) x 512 u64 (parity 0)
    ((u64*)ghf)[(size_t)gm * 1024 + j] = 0ull;
}

// Pre-shuffle weights into MFMA A-fragment order, bf16 (layout verified R2-R11).
__global__ void convert_weights(const float* __restrict__ Wih, const float* __restrict__ Whh,
                                const float* __restrict__ Wout,
                                unsigned short* __restrict__ wsA, unsigned short* __restrict__ wsO) {
    int gid = blockIdx.x * blockDim.x + threadIdx.x;
    if (gid < NMT * NKT * 64) {
        int lane = gid & 63, tile = gid >> 6;
        int kt = tile % NKT, mt = tile / NKT;
        int row = mt * 16 + (lane & 15);
        int kb  = kt * 32 + (lane >> 4) * 8;
        unsigned short o[8];
#pragma unroll
        for (int j = 0; j < 8; ++j) {
            int k = kb + j;
            float v = (k < EE) ? Wih[row * EE + k] : Whh[row * HH + (k - EE)];
            o[j] = f2bf(v);
        }
        uint4 pk;
        pk.x = o[0] | ((unsigned)o[1] << 16); pk.y = o[2] | ((unsigned)o[3] << 16);
        pk.z = o[4] | ((unsigned)o[5] << 16); pk.w = o[6] | ((unsigned)o[7] << 16);
        *(uint4*)(wsA + (size_t)gid * 8) = pk;
    } else {
        int g2 = gid - NMT * NKT * 64;
        if (g2 < NMT * NKT_O * 64) {
            int lane = g2 & 63, tile = g2 >> 6;
            int kt = tile % NKT_O, mt = tile / NKT_O;
            int row = mt * 16 + (lane & 15);
            int ub  = kt * 32 + (lane >> 4) * 8;
            unsigned short o[8];
#pragma unroll
            for (int j = 0; j < 8; ++j)
                o[j] = (row < LL) ? f2bf(Wout[row * HH + ub + j]) : (unsigned short)0;
            uint4 pk;
            pk.x = o[0] | ((unsigned)o[1] << 16); pk.y = o[2] | ((unsigned)o[3] << 16);
            pk.z = o[4] | ((unsigned)o[5] << 16); pk.w = o[6] | ((unsigned)o[7] << 16);
            *(uint4*)(wsO + (size_t)g2 * 8) = pk;
        }
    }
}

// Barrier-free 8-way split LSTM with producer-consumer wave specialization:
// wave 8 = dedicated poller (polls the group's 64 tags, one coalesced 256B
// load, relays min into LDS ready_s). Compute waves: data st8 -> wave-local
// vmcnt drain -> per-wave tag; consume after LDS spin. Zero block barriers
// in the K-loop; emb prefetch never drained on the critical path.
__launch_bounds__(NT, 1)
__global__ void lstm_spec_kernel(
    const int* __restrict__ tokens, const int* __restrict__ lengths,
    const int* __restrict__ labels, const float* __restrict__ emb,
    const float* __restrict__ bih,  const float* __restrict__ bhh,
    const float* __restrict__ bout,
    const unsigned short* __restrict__ wsA, const unsigned short* __restrict__ wsO,
    unsigned short* __restrict__ ghf, int* __restrict__ tags,
    float* __restrict__ out)
{
    __shared__ __align__(16) unsigned short wlds[8 * 12 * 64 * 8];   // 96 KB A-frags
    __shared__ int labv[SEQG];
    __shared__ int ready_s;

    const int tid = threadIdx.x;
    const int w   = tid >> 6;        // 0..8
    const int l   = tid & 63;
    const int lq  = l >> 4;
    const int ls  = l & 15;
    const int jj  = w & 1 ? 1 : (w >> 2) & 1;   // placeholder, recomputed below
    const int grp = blockIdx.x & (NGRP - 1);
    const int m   = blockIdx.x >> 5;
    const int n0  = grp * SEQG;

    // compute-wave role (only valid for w<8)
    const int jjc = (w >> 2) & 1;    // row half (0/1)
    const int cg  = w & 3;           // col group (16 seqs)
    (void)jj;

    int* const tagBase = tags + grp * 64;
    const int  myTag   = m * 8 + cg * 2 + jjc;

    int maxlen = lengths[n0 + l];
#pragma unroll
    for (int s = 1; s < 64; s <<= 1) maxlen = max(maxlen, __shfl_xor(maxlen, s, 64));
    const int len_s = lengths[n0 + cg * 16 + ls];
    const int myseq = n0 + cg * 16 + ls;

    if (tid < SEQG) labv[tid] = labels[n0 + tid];
    if (tid == 0) ready_s = 1;       // tags init to 1 by init kernel

    // ---- one-time: this member's A-frags (8 mt x 12 kt) -> LDS ----
    for (int idx = tid; idx < 8 * 12 * 64; idx += NT) {
        int mtl = idx / 768;
        int rem = idx - mtl * 768;
        int kt = rem >> 6, l2 = rem & 63;
        int g = mtl >> 1, j2 = mtl & 1;
        int gmt = 16 * g + 2 * m + j2;
        *(uint4*)&wlds[(size_t)idx * 8] =
            *(const uint4*)(wsA + ((size_t)(gmt * NKT + kt) * 64 + l2) * 8);
    }
    __syncthreads();   // wlds + labv + ready_s visible (only block barrier pre-epilogue)

    // compute-wave LDS spin (no MALL traffic)
    auto wave_wait = [&](int need) {
        while (__hip_atomic_load(&ready_s, __ATOMIC_ACQUIRE, __HIP_MEMORY_SCOPE_WORKGROUP) < need) {}
        asm volatile("" ::: "memory");
    };

    if (w == 8) {
        // ---- dedicated poller: continuously poll 64 tags, relay min to LDS ----
        int cur = 1;
        while (cur < maxlen + 1) {
            int f = __hip_atomic_load(&tagBase[l], __ATOMIC_RELAXED, __HIP_MEMORY_SCOPE_SYSTEM);
            f = min(f, __shfl_xor(f, 1, 64));
            f = min(f, __shfl_xor(f, 2, 64));
            f = min(f, __shfl_xor(f, 4, 64));
            f = min(f, __shfl_xor(f, 8, 64));
            f = min(f, __shfl_xor(f, 16, 64));
            f = min(f, __shfl_xor(f, 32, 64));
            f = __shfl(f, 0, 64);
            if (f > cur) {
                cur = f;
                if (l == 0)
                    __hip_atomic_store(&ready_s, cur, __ATOMIC_RELEASE, __HIP_MEMORY_SCOPE_WORKGROUP);
            }
        }
    } else {
        // ---- compute wave ----
        // biases in registers
        f32x4 biasv[4];
#pragma unroll
        for (int g = 0; g < 4; ++g)
#pragma unroll
            for (int r = 0; r < 4; ++r) {
                int row = 256 * g + 32 * m + 16 * jjc + 4 * lq + r;
                biasv[g][r] = bih[row] + bhh[row];
            }

        // h publish mapping: unit u = 16*jjc + 4*lq + r
        const int u8      = 2 * jjc + (lq >> 1);
        const int lanep_h = 16 * u8 + ls;
        const int joff_h  = 4 * (lq & 1);
        const size_t gb0  = ((size_t)((grp * NMEM + m) * 2 + 0) * 4 + cg) * 512 + (size_t)lanep_h * 8 + joff_h;
        const size_t gb1  = gb0 + 4 * 512;

        // x gather into registers: lane l -> emb[tok][kt*32 + (l>>4)*8 + j]
        const int xoff = (l >> 4) * 8;
        bf16x8 bx[4];
        {
            int tok = tokens[myseq * TT + 0];
            const float* er = emb + (size_t)tok * EE + xoff;
#pragma unroll
            for (int kt = 0; kt < 4; ++kt) {
                f32x4 a = *(const f32x4*)(er + kt * 32);
                f32x4 b = *(const f32x4*)(er + kt * 32 + 4);
                union { unsigned u[4]; bf16x8 v; } pk;
                pk.u[0] = f2bf(a[0]) | ((unsigned)f2bf(a[1]) << 16);
                pk.u[1] = f2bf(a[2]) | ((unsigned)f2bf(a[3]) << 16);
                pk.u[2] = f2bf(b[0]) | ((unsigned)f2bf(b[1]) << 16);
                pk.u[3] = f2bf(b[2]) | ((unsigned)f2bf(b[3]) << 16);
                bx[kt] = pk.v;
            }
        }

        // acc = bias + W_ih * x(0)
        f32x4 acc[4];
#pragma unroll
        for (int g = 0; g < 4; ++g) acc[g] = biasv[g];
#pragma unroll
        for (int kt = 0; kt < 4; ++kt)
#pragma unroll
            for (int g = 0; g < 4; ++g)
                acc[g] = __builtin_amdgcn_mfma_f32_16x16x32_bf16(
                    *(const bf16x8*)&wlds[(size_t)(((2 * g + jjc) * 12 + kt) * 64 + l) * 8],
                    bx[kt], acc[g], 0, 0, 0);

        float c_reg[4], h_reg[4];
#pragma unroll
        for (int r = 0; r < 4; ++r) { c_reg[r] = 0.0f; h_reg[r] = 0.0f; }

        // ---- recurrence: zero barriers, zero compute-wave MALL polling ----
        for (int t = 0; t < maxlen; ++t) {
            const int par = t & 1;

            // wait for all producers' h(t) (LDS spin; poller relays)
            wave_wait(t + 1);

            // 8 member tiles as B-frags from coherence point
            bf16x8 bp[8];
#pragma unroll
            for (int p = 0; p < 8; ++p) {
                size_t b = ((size_t)((grp * NMEM + p) * 2 + par) * 4 + cg) * 512;
                bp[p] = ld16_sys(&ghf[b + (size_t)l * 8]);
            }
            // h-part MFMAs
#pragma unroll
            for (int p = 0; p < 8; ++p)
#pragma unroll
                for (int g = 0; g < 4; ++g)
                    acc[g] = __builtin_amdgcn_mfma_f32_16x16x32_bf16(
                        *(const bf16x8*)&wlds[(size_t)(((2 * g + jjc) * 12 + 4 + p) * 64 + l) * 8],
                        bp[p], acc[g], 0, 0, 0);

            // in-register cell update
            const bool live = (t < len_s);
#pragma unroll
            for (int r = 0; r < 4; ++r) {
                if (live) {
                    float ig = sigf(acc[0][r]);
                    float fg = sigf(acc[1][r]);
                    float gg = tanh_fast(acc[2][r]);
                    float og = sigf(acc[3][r]);
                    float cc = fg * c_reg[r] + ig * gg;
                    c_reg[r] = cc;
                    h_reg[r] = og * tanh_fast(cc);
                }
            }

            // publish h(t+1): data st8 -> wave-local drain -> tag = t+2
            {
                uint2 hp;
                hp.x = f2bf(h_reg[0]) | ((unsigned)f2bf(h_reg[1]) << 16);
                hp.y = f2bf(h_reg[2]) | ((unsigned)f2bf(h_reg[3]) << 16);
                st8_sys(&ghf[par ? gb0 : gb1], hp.x, hp.y);
            }
            __builtin_amdgcn_s_waitcnt(0);
            asm volatile("" ::: "memory");
            if (l == 0)
                __hip_atomic_store(&tagBase[myTag], t + 2, __ATOMIC_RELAXED, __HIP_MEMORY_SCOPE_SYSTEM);

            // off critical path: gather x(t+1), pre-accumulate x-part
            if (t + 1 < maxlen) {
                int tok = tokens[myseq * TT + t + 1];
                const float* er = emb + (size_t)tok * EE + xoff;
#pragma unroll
                for (int kt = 0; kt < 4; ++kt) {
                    f32x4 a = *(const f32x4*)(er + kt * 32);
                    f32x4 b = *(const f32x4*)(er + kt * 32 + 4);
                    union { unsigned u[4]; bf16x8 v; } pk;
                    pk.u[0] = f2bf(a[0]) | ((unsigned)f2bf(a[1]) << 16);
                    pk.u[1] = f2bf(a[2]) | ((unsigned)f2bf(a[3]) << 16);
                    pk.u[2] = f2bf(b[0]) | ((unsigned)f2bf(b[1]) << 16);
                    pk.u[3] = f2bf(b[2]) | ((unsigned)f2bf(b[3]) << 16);
                    bx[kt] = pk.v;
                }
#pragma unroll
                for (int g = 0; g < 4; ++g) acc[g] = biasv[g];
#pragma unroll
                for (int kt = 0; kt < 4; ++kt)
#pragma unroll
                    for (int g = 0; g < 4; ++g)
                        acc[g] = __builtin_amdgcn_mfma_f32_16x16x32_bf16(
                            *(const bf16x8*)&wlds[(size_t)(((2 * g + jjc) * 12 + kt) * 64 + l) * 8],
                            bx[kt], acc[g], 0, 0, 0);
            }
        }

        // ---- epilogue 1: embeds = mean(c_f) for own 32 units ----
#pragma unroll
        for (int r = 0; r < 4; ++r) {
            float v = c_reg[r];
            v += __shfl_xor(v, 1, 64);
            v += __shfl_xor(v, 2, 64);
            v += __shfl_xor(v, 4, 64);
            v += __shfl_xor(v, 8, 64);
            if (ls == 0)
                atomicAdd(&out[32 * m + 16 * jjc + 4 * lq + r], v * (1.0f / NSEQ));
        }
    }

    // ---- epilogue 2 (member 0): logits GEMM + log-softmax; all 9 waves join barriers ----
    if (m == 0) {
        if (w < 8) wave_wait(maxlen + 1);   // poller already exited having relayed it
        const int fin = maxlen & 1;
        float* lg = (float*)wlds;            // reuse: 16 seqs x 1024 logits (64 KB)
        float lossAcc = 0.0f;

        for (int cgo = 0; cgo < 4; ++cgo) {
            bf16x8 bq[8];
            if (w < 8) {
#pragma unroll
                for (int p = 0; p < 8; ++p) {
                    size_t b = ((size_t)((grp * NMEM + p) * 2 + fin) * 4 + cgo) * 512;
                    bq[p] = ld16_sys(&ghf[b + (size_t)l * 8]);
                }
            }
            __syncthreads();   // prev cgo softmax reads / main-loop wlds reads done
            if (w < 8) {
#pragma unroll
                for (int i = 0; i < 8; ++i) {
                    int mt = 8 * w + i;
                    f32x4 a = {0.0f, 0.0f, 0.0f, 0.0f};
#pragma unroll
                    for (int p = 0; p < 8; ++p)
                        a = __builtin_amdgcn_mfma_f32_16x16x32_bf16(
                            *(const bf16x8*)(wsO + ((size_t)(mt * NKT_O + p) * 64 + l) * 8),
                            bq[p], a, 0, 0, 0);
#pragma unroll
                    for (int r = 0; r < 4; ++r) {
                        int cls = 16 * mt + 4 * lq + r;
                        lg[(size_t)ls * 1024 + cls] = (cls < LL) ? (a[r] + bout[cls]) : -INFINITY;
                    }
                }
            }
            __syncthreads();
            if (w < 8) {
                const int s2 = tid >> 5;
                const int i2 = tid & 31;
                const float* row = &lg[(size_t)s2 * 1024];
                float mx = -INFINITY;
#pragma unroll
                for (int k = 0; k < 32; ++k) mx = fmaxf(mx, row[i2 + 32 * k]);
                mx = fmaxf(mx, __shfl_xor(mx, 1, 64));
                mx = fmaxf(mx, __shfl_xor(mx, 2, 64));
                mx = fmaxf(mx, __shfl_xor(mx, 4, 64));
                mx = fmaxf(mx, __shfl_xor(mx, 8, 64));
                mx = fmaxf(mx, __shfl_xor(mx, 16, 64));
                float sm = 0.0f;
#pragma unroll
                for (int k = 0; k < 32; ++k) sm += __expf(row[i2 + 32 * k] - mx);
                sm += __shfl_xor(sm, 1, 64);
                sm += __shfl_xor(sm, 2, 64);
                sm += __shfl_xor(sm, 4, 64);
                sm += __shfl_xor(sm, 8, 64);
                sm += __shfl_xor(sm, 16, 64);
                if (i2 == 0 && s2 < 16) {
                    int lab = labv[cgo * 16 + s2];
                    float lp = row[lab] - mx - __logf(sm);
                    lossAcc += -lp;
                }
            }
        }
        if (w < 8 && (tid & 31) == 0)
            atomicAdd(&out[HH], lossAcc * (1.0f / NSEQ));
    }
}

extern "C" void kernel_launch(void* const* d_in, const int* in_sizes, int n_in,
                              void* d_out, int out_size, void* d_ws, size_t ws_size,
                              hipStream_t stream)
{
    const int*   tokens  = (const int*)d_in[0];
    const int*   lengths = (const int*)d_in[1];
    const int*   labels  = (const int*)d_in[2];
    const float* emb     = (const float*)d_in[3];
    const float* Wih     = (const float*)d_in[4];
    const float* Whh     = (const float*)d_in[5];
    const float* bih     = (const float*)d_in[6];
    const float* bhh     = (const float*)d_in[7];
    const float* Wout    = (const float*)d_in[8];
    const float* bout    = (const float*)d_in[9];
    float* out = (float*)d_out;

    unsigned short* wsA  = (unsigned short*)d_ws;
    unsigned short* wsO  = wsA + WSA_ELEMS;
    unsigned short* ghf  = wsO + WSO_ELEMS;
    int*            tg   = (int*)(ghf + GHF_SHORTS);   // 8 KB tags; ws ~3.3 MB

    hipLaunchKernelGGL(init_all_kernel, dim3(256), dim3(512), 0, stream, out, tg, ghf);
    {
        int nthr = NMT * NKT * 64 + NMT * NKT_O * 64;
        hipLaunchKernelGGL(convert_weights, dim3((nthr + 255) / 256), dim3(256), 0, stream,
                           Wih, Whh, Wout, wsA, wsO);
    }
    hipLaunchKernelGGL(lstm_spec_kernel, dim3(NGRP * NMEM), dim3(NT), 0, stream,
                       tokens, lengths, labels, emb, bih, bhh, bout, wsA, wsO, ghf, tg, out);
}

// Round 13
// 726.335 us; speedup vs baseline: 2.0026x; 2.0026x over previous
//
#include <hip/hip_runtime.h>
#include <hip/hip_bf16.h>
#include <math.h>

// Problem constants
#define NSEQ 2048
#define TT   128
#define EE   128
#define HH   256
#define GG   1024
#define LL   1000
#define NT   512        // 8 waves
#define NGRP 32         // groups of 64 seqs
#define NMEM 8          // members (blocks) per group; member owns 32 h-units
#define SEQG 64
#define NKT  12         // K-tiles of 32: 4 x + 8 h
#define NMT  64
#define NKT_O 8
#define WSA_ELEMS (NMT * NKT * 64 * 8)      // 768 KB bf16
#define WSO_ELEMS (NMT * NKT_O * 64 * 8)    // 512 KB bf16
// ghf: [grp][member][parity][cg][64 lanes][8 shorts] = 2 MB
#define GHF_SHORTS ((size_t)NGRP * NMEM * 2 * 4 * 64 * 8)

typedef __attribute__((ext_vector_type(8))) short bf16x8;
typedef __attribute__((ext_vector_type(4))) float f32x4;
typedef unsigned long long u64;

__device__ __forceinline__ unsigned short f2bf(float f) {
    union { float f; unsigned u; } v; v.f = f;
    unsigned r = v.u + 0x7FFF + ((v.u >> 16) & 1);   // RNE
    return (unsigned short)(r >> 16);
}
__device__ __forceinline__ float sigf(float x) { return 1.0f / (1.0f + __expf(-x)); }
__device__ __forceinline__ float tanh_fast(float x) { return 1.0f - 2.0f / (1.0f + __expf(2.0f * x)); }

// system-scope relaxed 8B ops: sc0+sc1 (served at coherence point) — NO wbl2/inv
__device__ __forceinline__ void st8_sys(unsigned short* p, unsigned lo, unsigned hi) {
    u64 v = (u64)lo | ((u64)hi << 32);
    __hip_atomic_store((u64*)p, v, __ATOMIC_RELAXED, __HIP_MEMORY_SCOPE_SYSTEM);
}
__device__ __forceinline__ uint4 ld16_sys_u(const unsigned short* p) {
    u64 lo = __hip_atomic_load((const u64*)p,       __ATOMIC_RELAXED, __HIP_MEMORY_SCOPE_SYSTEM);
    u64 hi = __hip_atomic_load((const u64*)(p + 4), __ATOMIC_RELAXED, __HIP_MEMORY_SCOPE_SYSTEM);
    union { u64 q[2]; uint4 v; } u; u.q[0] = lo; u.q[1] = hi;
    return u.v;
}
__device__ __forceinline__ bf16x8 ld16_sys(const unsigned short* p) {
    union { uint4 q; bf16x8 v; } u; u.q = ld16_sys_u(p);
    return u.v;
}

__global__ void init_all_kernel(float* out, int* flags) {
    int i = blockIdx.x * blockDim.x + threadIdx.x;
    if (i < HH + 1) out[i] = 0.0f;
    if (i < NGRP * NMEM) flags[i] = 0;
}

// Pre-shuffle weights into MFMA A-fragment order, bf16 (layout verified R2-R12).
__global__ void convert_weights(const float* __restrict__ Wih, const float* __restrict__ Whh,
                                const float* __restrict__ Wout,
                                unsigned short* __restrict__ wsA, unsigned short* __restrict__ wsO) {
    int gid = blockIdx.x * blockDim.x + threadIdx.x;
    if (gid < NMT * NKT * 64) {
        int lane = gid & 63, tile = gid >> 6;
        int kt = tile % NKT, mt = tile / NKT;
        int row = mt * 16 + (lane & 15);
        int kb  = kt * 32 + (lane >> 4) * 8;
        unsigned short o[8];
#pragma unroll
        for (int j = 0; j < 8; ++j) {
            int k = kb + j;
            float v = (k < EE) ? Wih[row * EE + k] : Whh[row * HH + (k - EE)];
            o[j] = f2bf(v);
        }
        uint4 pk;
        pk.x = o[0] | ((unsigned)o[1] << 16); pk.y = o[2] | ((unsigned)o[3] << 16);
        pk.z = o[4] | ((unsigned)o[5] << 16); pk.w = o[6] | ((unsigned)o[7] << 16);
        *(uint4*)(wsA + (size_t)gid * 8) = pk;
    } else {
        int g2 = gid - NMT * NKT * 64;
        if (g2 < NMT * NKT_O * 64) {
            int lane = g2 & 63, tile = g2 >> 6;
            int kt = tile % NKT_O, mt = tile / NKT_O;
            int row = mt * 16 + (lane & 15);
            int ub  = kt * 32 + (lane >> 4) * 8;
            unsigned short o[8];
#pragma unroll
            for (int j = 0; j < 8; ++j)
                o[j] = (row < LL) ? f2bf(Wout[row * HH + ub + j]) : (unsigned short)0;
            uint4 pk;
            pk.x = o[0] | ((unsigned)o[1] << 16); pk.y = o[2] | ((unsigned)o[3] << 16);
            pk.z = o[4] | ((unsigned)o[5] << 16); pk.w = o[6] | ((unsigned)o[7] << 16);
            *(uint4*)(wsO + (size_t)g2 * 8) = pk;
        }
    }
}

// R8 structure (measured best: 667us) + cooperative partner-tile load:
// after relay_wait, waves 0-6 fetch one partner 4KB tile each into LDS pbuf
// (halves MALL reads, wave-parallel issue); all waves then ds_read B-frags.
__launch_bounds__(NT, 1)
__global__ void lstm_group_kernel(
    const int* __restrict__ tokens, const int* __restrict__ lengths,
    const int* __restrict__ labels, const float* __restrict__ emb,
    const float* __restrict__ bih,  const float* __restrict__ bhh,
    const float* __restrict__ bout,
    const unsigned short* __restrict__ wsA, const unsigned short* __restrict__ wsO,
    unsigned short* __restrict__ ghf, int* __restrict__ flags,
    float* __restrict__ out)
{
    __shared__ __align__(16) unsigned short wlds[8 * 12 * 64 * 8];   // 96 KB A-frags
    __shared__ __align__(16) unsigned short xfS[4 * 4 * 64 * 8];     // 16 KB x B-frags
    __shared__ __align__(16) unsigned short hf[2 * 4 * 64 * 8];      // 8 KB own-h (dbuf)
    __shared__ __align__(16) unsigned short pbuf[7 * 4 * 64 * 8];    // 28 KB partner tiles
    __shared__ int   labv[SEQG];
    __shared__ int   ready_s;

    const int tid = threadIdx.x;
    const int w   = tid >> 6;
    const int l   = tid & 63;
    const int lq  = l >> 4;
    const int ls  = l & 15;
    const int jj  = w >> 2;        // row half (0/1)
    const int cg  = w & 3;         // col group (16 seqs)
    const int grp = blockIdx.x & (NGRP - 1);
    const int m   = blockIdx.x >> 5;
    const int n0  = grp * SEQG;

    int* const flagBase = flags + grp * NMEM;

    int maxlen = lengths[n0 + l];
#pragma unroll
    for (int s = 1; s < 64; s <<= 1) maxlen = max(maxlen, __shfl_xor(maxlen, s, 64));
    const int len_s = lengths[n0 + cg * 16 + ls];

    if (tid < SEQG) labv[tid] = labels[n0 + tid];
    if (tid == 0) ready_s = 0;

    // biases in registers
    f32x4 biasv[4];
#pragma unroll
    for (int g = 0; g < 4; ++g)
#pragma unroll
        for (int r = 0; r < 4; ++r) {
            int row = 256 * g + 32 * m + 16 * jj + 4 * lq + r;
            biasv[g][r] = bih[row] + bhh[row];
        }

    // one-time: this member's A-frags (8 mt x 12 kt) -> LDS
    for (int idx = tid; idx < 8 * 12 * 64; idx += NT) {
        int mtl = idx / 768;
        int rem = idx - mtl * 768;
        int kt = rem >> 6, l2 = rem & 63;
        int g = mtl >> 1, j2 = mtl & 1;
        int gmt = 16 * g + 2 * m + j2;
        *(uint4*)&wlds[(size_t)idx * 8] =
            *(const uint4*)(wsA + ((size_t)(gmt * NKT + kt) * 64 + l2) * 8);
    }

    // zero hf buf0 + ghf parity0 slice (h(0) = 0)
    if (tid < 256) {
        uint4 z = {0, 0, 0, 0};
        *(uint4*)&hf[(size_t)tid * 8] = z;
        size_t base = ((size_t)((grp * NMEM + m) * 2 + 0) * 4) * 512 + (size_t)tid * 8;
        st8_sys(&ghf[base], 0, 0);
        st8_sys(&ghf[base + 4], 0, 0);
    }

    // x staging map: thread -> (seq, 16-dim octet)
    const int xs_s   = tid & 63;
    const int xs_oct = tid >> 6;

    auto stageX = [&](const f32x4* xv) {
#pragma unroll
        for (int dc = 0; dc < 4; ++dc) {
            int d0 = 16 * xs_oct + 4 * dc;
            int kt = d0 >> 5, cgs = xs_s >> 4;
            int lanep = (xs_s & 15) + 16 * ((d0 >> 3) & 3);
            uint2 pk;
            pk.x = f2bf(xv[dc][0]) | ((unsigned)f2bf(xv[dc][1]) << 16);
            pk.y = f2bf(xv[dc][2]) | ((unsigned)f2bf(xv[dc][3]) << 16);
            *(uint2*)&xfS[(size_t)((kt * 4 + cgs) * 64 + lanep) * 8 + (d0 & 4)] = pk;
        }
    };

    // stage x(0)
    {
        int tok = tokens[(n0 + xs_s) * TT + 0];
        const float* er = emb + (size_t)tok * EE + 16 * xs_oct;
        f32x4 x0[4];
#pragma unroll
        for (int dc = 0; dc < 4; ++dc) x0[dc] = *(const f32x4*)(er + 4 * dc);
        stageX(x0);
    }
    __syncthreads();   // drains ghf zero stores + x(0) staging + wlds
    if (tid == 0)
        __hip_atomic_store(&flagBase[m], 1, __ATOMIC_RELAXED, __HIP_MEMORY_SCOPE_SYSTEM);

    // prefetch x(1)
    f32x4 xv[4];
    if (maxlen > 1) {
        int tok = tokens[(n0 + xs_s) * TT + 1];
        const float* er = emb + (size_t)tok * EE + 16 * xs_oct;
#pragma unroll
        for (int dc = 0; dc < 4; ++dc) xv[dc] = *(const f32x4*)(er + 4 * dc);
    }

    // acc = bias + xpart(x(0))
    f32x4 acc[4], accN[4];
#pragma unroll
    for (int g = 0; g < 4; ++g) acc[g] = biasv[g];
#pragma unroll
    for (int kt = 0; kt < 4; ++kt) {
        const bf16x8 bx = *(const bf16x8*)&xfS[(size_t)((kt * 4 + cg) * 64 + l) * 8];
#pragma unroll
        for (int g = 0; g < 4; ++g)
            acc[g] = __builtin_amdgcn_mfma_f32_16x16x32_bf16(
                *(const bf16x8*)&wlds[(size_t)(((2 * g + jj) * 12 + kt) * 64 + l) * 8],
                bx, acc[g], 0, 0, 0);
    }
    __syncthreads();   // xfS reads done; iter 0 may restage

    // relay wait: wave0 polls flags with s_sleep pacing; others spin on LDS
    auto relay_wait = [&](int need) {
        if (w == 0) {
            int f;
            do {
                f = 0x7fffffff;
                if (l < NMEM)
                    f = __hip_atomic_load(&flagBase[l], __ATOMIC_RELAXED, __HIP_MEMORY_SCOPE_SYSTEM);
                f = min(f, __shfl_xor(f, 1, 64));
                f = min(f, __shfl_xor(f, 2, 64));
                f = min(f, __shfl_xor(f, 4, 64));
                f = __shfl(f, 0, 64);
                if (f < need) __builtin_amdgcn_s_sleep(2);
            } while (f < need);
            __hip_atomic_store(&ready_s, need, __ATOMIC_RELEASE, __HIP_MEMORY_SCOPE_WORKGROUP);
        } else {
            while (__hip_atomic_load(&ready_s, __ATOMIC_ACQUIRE, __HIP_MEMORY_SCOPE_WORKGROUP) < need)
                __builtin_amdgcn_s_sleep(1);
        }
        asm volatile("" ::: "memory");
    };

    float c_reg[4], h_reg[4];
#pragma unroll
    for (int r = 0; r < 4; ++r) { c_reg[r] = 0.0f; h_reg[r] = 0.0f; }

    // h publish mapping: unit u = 16*jj + 4*lq + r in member's 32-k tile
    const int u8      = 2 * jj + (lq >> 1);
    const int lanep_h = 16 * u8 + ls;
    const int joff_h  = 4 * (lq & 1);
    const size_t gb0  = ((size_t)((grp * NMEM + m) * 2 + 0) * 4 + cg) * 512 + (size_t)lanep_h * 8 + joff_h;
    const size_t gb1  = gb0 + 4 * 512;

    // coop-load role: wave w<7 fetches partner pw's full 4KB tile
    const int pw = (w < 7) ? (w + (w >= m ? 1 : 0)) : 0;

    // ---- recurrence (steady state: xpart(t) already in acc) ----
    for (int t = 0; t < maxlen; ++t) {
        const int cur = t & 1, nxt = cur ^ 1;
        const bool doX = (t + 1 < maxlen);

        // head: stage x(t+1) from regs (partner-independent)
        if (doX) stageX(xv);
        const bf16x8 bo = *(const bf16x8*)&hf[(size_t)((cur * 4 + cg) * 64 + l) * 8];
        if (doX) __syncthreads();   // barrier A: staging visible

        // prefetch x(t+2) (drains at barrier B, a full iter away)
        if (t + 2 < maxlen) {
            int tok = tokens[(n0 + xs_s) * TT + t + 2];
            const float* er = emb + (size_t)tok * EE + 16 * xs_oct;
#pragma unroll
            for (int dc = 0; dc < 4; ++dc) xv[dc] = *(const f32x4*)(er + 4 * dc);
        }

        // xpart(t+1) into accN — fills the wait window
        if (doX) {
#pragma unroll
            for (int g = 0; g < 4; ++g) accN[g] = biasv[g];
#pragma unroll
            for (int kt = 0; kt < 4; ++kt) {
                const bf16x8 bx = *(const bf16x8*)&xfS[(size_t)((kt * 4 + cg) * 64 + l) * 8];
#pragma unroll
                for (int g = 0; g < 4; ++g)
                    accN[g] = __builtin_amdgcn_mfma_f32_16x16x32_bf16(
                        *(const bf16x8*)&wlds[(size_t)(((2 * g + jj) * 12 + kt) * 64 + l) * 8],
                        bx, accN[g], 0, 0, 0);
            }
        }

        // wait for all members' h(t)
        relay_wait(t + 1);

        // cooperative fetch: wave w<7 loads partner pw's 4KB tile (4 coalesced
        // 16B chunks/lane) — wave-parallel, deduped (each subtile fetched once)
        uint4 ptile[4];
        if (w < 7) {
            const unsigned short* src = ghf + ((size_t)((grp * NMEM + pw) * 2 + cur) * 2048);
#pragma unroll
            for (int k = 0; k < 4; ++k)
                ptile[k] = ld16_sys_u(src + (size_t)(l + 64 * k) * 8);
        }

        // own-h part (hides partner-fetch latency)
#pragma unroll
        for (int g = 0; g < 4; ++g)
            acc[g] = __builtin_amdgcn_mfma_f32_16x16x32_bf16(
                *(const bf16x8*)&wlds[(size_t)(((2 * g + jj) * 12 + 4 + m) * 64 + l) * 8],
                bo, acc[g], 0, 0, 0);

        // spill partner tiles to LDS, make visible
        if (w < 7) {
#pragma unroll
            for (int k = 0; k < 4; ++k)
                *(uint4*)&pbuf[((size_t)w * 256 + l + 64 * k) * 8] = ptile[k];
        }
        __syncthreads();   // barrier C: pbuf visible

        // partner-h parts from LDS (conflict-free ds_read_b128)
#pragma unroll
        for (int i = 0; i < 7; ++i) {
            int p = i + (i >= m ? 1 : 0);
            const bf16x8 bp = *(const bf16x8*)&pbuf[((size_t)i * 256 + cg * 64 + l) * 8];
#pragma unroll
            for (int g = 0; g < 4; ++g)
                acc[g] = __builtin_amdgcn_mfma_f32_16x16x32_bf16(
                    *(const bf16x8*)&wlds[(size_t)(((2 * g + jj) * 12 + 4 + p) * 64 + l) * 8],
                    bp, acc[g], 0, 0, 0);
        }

        // in-register cell update
        const bool live = (t < len_s);
#pragma unroll
        for (int r = 0; r < 4; ++r) {
            if (live) {
                float ig = sigf(acc[0][r]);
                float fg = sigf(acc[1][r]);
                float gg = tanh_fast(acc[2][r]);
                float og = sigf(acc[3][r]);
                float cc = fg * c_reg[r] + ig * gg;
                c_reg[r] = cc;
                h_reg[r] = og * tanh_fast(cc);
            }
        }

        // carry pipelined xpart
        if (doX) {
#pragma unroll
            for (int g = 0; g < 4; ++g) acc[g] = accN[g];
        }

        // publish h(t+1): LDS nxt + ghf (system store), parity (t+1)&1
        {
            uint2 hp;
            hp.x = f2bf(h_reg[0]) | ((unsigned)f2bf(h_reg[1]) << 16);
            hp.y = f2bf(h_reg[2]) | ((unsigned)f2bf(h_reg[3]) << 16);
            *(uint2*)&hf[(size_t)((nxt * 4 + cg) * 64 + lanep_h) * 8 + joff_h] = hp;
            st8_sys(&ghf[((t + 1) & 1) ? gb1 : gb0], hp.x, hp.y);
        }

        __syncthreads();   // barrier B: drains ghf stores (+ x prefetch loads)
        if (tid == 0)
            __hip_atomic_store(&flagBase[m], t + 2, __ATOMIC_RELAXED, __HIP_MEMORY_SCOPE_SYSTEM);
    }

    // ---- epilogue 1: embeds = mean(c_f) for own 32 units ----
#pragma unroll
    for (int r = 0; r < 4; ++r) {
        float v = c_reg[r];
        v += __shfl_xor(v, 1, 64);
        v += __shfl_xor(v, 2, 64);
        v += __shfl_xor(v, 4, 64);
        v += __shfl_xor(v, 8, 64);
        if (ls == 0)
            atomicAdd(&out[32 * m + 16 * jj + 4 * lq + r], v * (1.0f / NSEQ));
    }

    // ---- epilogue 2 (member 0): logits GEMM + log-softmax ----
    if (m == 0) {
        relay_wait(maxlen + 1);
        const int fin = maxlen & 1;
        float* lg = (float*)wlds;            // reuse: 16 seqs x 1024 logits
        float lossAcc = 0.0f;

        for (int cgo = 0; cgo < 4; ++cgo) {
            bf16x8 bq[8];
#pragma unroll
            for (int p = 0; p < 8; ++p) {
                size_t b = ((size_t)((grp * NMEM + p) * 2 + fin) * 4 + cgo) * 512;
                bq[p] = ld16_sys(&ghf[b + (size_t)l * 8]);
            }
            __syncthreads();
#pragma unroll
            for (int i = 0; i < 8; ++i) {
                int mt = 8 * w + i;
                f32x4 a = {0.0f, 0.0f, 0.0f, 0.0f};
#pragma unroll
                for (int p = 0; p < 8; ++p)
                    a = __builtin_amdgcn_mfma_f32_16x16x32_bf16(
                        *(const bf16x8*)(wsO + ((size_t)(mt * NKT_O + p) * 64 + l) * 8),
                        bq[p], a, 0, 0, 0);
#pragma unroll
                for (int r = 0; r < 4; ++r) {
                    int cls = 16 * mt + 4 * lq + r;
                    lg[(size_t)ls * 1024 + cls] = (cls < LL) ? (a[r] + bout[cls]) : -INFINITY;
                }
            }
            __syncthreads();
            const int s2 = tid >> 5;
            const int i2 = tid & 31;
            const float* row = &lg[(size_t)s2 * 1024];
            float mx = -INFINITY;
#pragma unroll
            for (int k = 0; k < 32; ++k) mx = fmaxf(mx, row[i2 + 32 * k]);
            mx = fmaxf(mx, __shfl_xor(mx, 1, 64));
            mx = fmaxf(mx, __shfl_xor(mx, 2, 64));
            mx = fmaxf(mx, __shfl_xor(mx, 4, 64));
            mx = fmaxf(mx, __shfl_xor(mx, 8, 64));
            mx = fmaxf(mx, __shfl_xor(mx, 16, 64));
            float sm = 0.0f;
#pragma unroll
            for (int k = 0; k < 32; ++k) sm += __expf(row[i2 + 32 * k] - mx);
            sm += __shfl_xor(sm, 1, 64);
            sm += __shfl_xor(sm, 2, 64);
            sm += __shfl_xor(sm, 4, 64);
            sm += __shfl_xor(sm, 8, 64);
            sm += __shfl_xor(sm, 16, 64);
            if (i2 == 0) {
                int lab = labv[cgo * 16 + s2];
                float lp = row[lab] - mx - __logf(sm);
                lossAcc += -lp;
            }
        }
        if ((tid & 31) == 0)
            atomicAdd(&out[HH], lossAcc * (1.0f / NSEQ));
    }
}

extern "C" void kernel_launch(void* const* d_in, const int* in_sizes, int n_in,
                              void* d_out, int out_size, void* d_ws, size_t ws_size,
                              hipStream_t stream)
{
    const int*   tokens  = (const int*)d_in[0];
    const int*   lengths = (const int*)d_in[1];
    const int*   labels  = (const int*)d_in[2];
    const float* emb     = (const float*)d_in[3];
    const float* Wih     = (const float*)d_in[4];
    const float* Whh     = (const float*)d_in[5];
    const float* bih     = (const float*)d_in[6];
    const float* bhh     = (const float*)d_in[7];
    const float* Wout    = (const float*)d_in[8];
    const float* bout    = (const float*)d_in[9];
    float* out = (float*)d_out;

    unsigned short* wsA  = (unsigned short*)d_ws;
    unsigned short* wsO  = wsA + WSA_ELEMS;
    unsigned short* ghf  = wsO + WSO_ELEMS;
    int*            flg  = (int*)(ghf + GHF_SHORTS);   // 256 ints; ws ~3.3 MB

    hipLaunchKernelGGL(init_all_kernel, dim3(1), dim3(512), 0, stream, out, flg);
    {
        int nthr = NMT * NKT * 64 + NMT * NKT_O * 64;
        hipLaunchKernelGGL(convert_weights, dim3((nthr + 255) / 256), dim3(256), 0, stream,
                           Wih, Whh, Wout, wsA, wsO);
    }
    hipLaunchKernelGGL(lstm_group_kernel, dim3(NGRP * NMEM), dim3(NT), 0, stream,
                       tokens, lengths, labels, emb, bih, bhh, bout, wsA, wsO, ghf, flg, out);
}